// Round 5
// baseline (580.058 us; speedup 1.0000x reference)
//
#include <hip/hip_runtime.h>

#define TILE_ATOMS 10000               // 10 tiles for 100K atoms
#define TILE_FLOATS (TILE_ATOMS * 4)   // 160000 B LDS = full CU capacity
#define BLOCK 1024
#define CHUNKS 16                      // 8 XCDs x 2 chunks each

// Detect whether neighbor_indices is int64 or int32 (odd u32 words all zero
// => int64 high halves). 4-byte atomic-written flag: replay-safe (r1/r2/r4).
__global__ void detect_idx64_kernel(const unsigned int* __restrict__ idx_u32,
                                    int* __restrict__ flag) {
    __shared__ int nonzero;
    if (threadIdx.x == 0) nonzero = 0;
    __syncthreads();
    unsigned int v = idx_u32[2 * (threadIdx.x +   0) + 1]
                   | idx_u32[2 * (threadIdx.x + 256) + 1]
                   | idx_u32[2 * (threadIdx.x + 512) + 1]
                   | idx_u32[2 * (threadIdx.x + 768) + 1];
    if (v != 0u) atomicAdd(&nonzero, 1);
    __syncthreads();
    if (threadIdx.x == 0) *flag = (nonzero == 0) ? 1 : 0;  // 1 => int64
}

__device__ __forceinline__ void proc_edge(
    int ai, int aj, int e, int tbase,
    const float4* __restrict__ charges, const float* __restrict__ dist,
    float* __restrict__ tile)
{
    unsigned ri = (unsigned)(ai - tbase);
    unsigned rj = (unsigned)(aj - tbase);
    if (ri < TILE_ATOMS || rj < TILE_ATOMS) {
        float d = dist[e];
        // erfc(d/sqrt(2))/d with the final /2 folded in; rcp is 1-ulp-ish.
        float p = 0.5f * erfcf(d * 0.70710678118654752440f)
                       * __builtin_amdgcn_rcpf(d);
        if (ri < TILE_ATOMS) {
            float4 cj = charges[aj];
            atomicAdd(&tile[ri * 4 + 0], cj.x * p);
            atomicAdd(&tile[ri * 4 + 1], cj.y * p);
            atomicAdd(&tile[ri * 4 + 2], cj.z * p);
            atomicAdd(&tile[ri * 4 + 3], cj.w * p);
        }
        if (rj < TILE_ATOMS) {
            float4 ci = charges[ai];
            atomicAdd(&tile[rj * 4 + 0], ci.x * p);
            atomicAdd(&tile[rj * 4 + 1], ci.y * p);
            atomicAdd(&tile[rj * 4 + 2], ci.z * p);
            atomicAdd(&tile[rj * 4 + 3], ci.w * p);
        }
    }
}

// Fused: block handles (tile t, chunk c). XCD-affinity mapping: the ntiles
// blocks sharing a chunk all sit on one XCD (bid&7 == XCD, m09) and scan it
// in lockstep -> the moving read window stays L2-resident. LDS-accumulate,
// then flush the tile into pre-zeroed d_out with HW f32 atomics (memory-side,
// replay-safe; plain-store handoff is not — r3 lesson).
__global__ __launch_bounds__(BLOCK, 1) void fused_tile_kernel(
    const float4* __restrict__ charges,   // [n_atoms]
    const void*  __restrict__ idx,        // [n_edges][2] int32 or int64
    const float* __restrict__ dist,       // [n_edges]
    float*       __restrict__ out,        // [n_atoms*4], pre-zeroed
    const int*   __restrict__ flag64,
    int n_edges, int n_atoms, int ntiles, int epc)
{
    __shared__ float tile[TILE_FLOATS];
    int x  = blockIdx.x & 7;              // XCD (round-robin dispatch)
    int m  = blockIdx.x >> 3;
    int t  = m % ntiles;                  // tile: varies fastest within XCD
    int cw = m / ntiles;                  // 0..CHUNKS/8-1
    int c  = x * (CHUNKS / 8) + cw;       // chunk, XCD-private
    int tbase = t * TILE_ATOMS;
    for (int i = threadIdx.x; i < TILE_FLOATS; i += BLOCK) tile[i] = 0.f;
    bool f64 = (*flag64 != 0);
    __syncthreads();

    int e0 = c * epc;
    int e1 = min(n_edges, e0 + epc);

    if (f64) {
        const longlong2* p64 = (const longlong2*)idx;
        int e = e0 + (int)threadIdx.x;
        // 4x batched: 4 independent coalesced 16B loads in flight per wave.
        for (; e + 3 * BLOCK < e1; e += 4 * BLOCK) {
            longlong2 v0 = p64[e];
            longlong2 v1 = p64[e +     BLOCK];
            longlong2 v2 = p64[e + 2 * BLOCK];
            longlong2 v3 = p64[e + 3 * BLOCK];
            proc_edge((int)v0.x, (int)v0.y, e,             tbase, charges, dist, tile);
            proc_edge((int)v1.x, (int)v1.y, e +     BLOCK, tbase, charges, dist, tile);
            proc_edge((int)v2.x, (int)v2.y, e + 2 * BLOCK, tbase, charges, dist, tile);
            proc_edge((int)v3.x, (int)v3.y, e + 3 * BLOCK, tbase, charges, dist, tile);
        }
        for (; e < e1; e += BLOCK) {
            longlong2 v = p64[e];
            proc_edge((int)v.x, (int)v.y, e, tbase, charges, dist, tile);
        }
    } else {
        const int2* p32 = (const int2*)idx;
        int e = e0 + (int)threadIdx.x;
        for (; e + 3 * BLOCK < e1; e += 4 * BLOCK) {
            int2 v0 = p32[e];
            int2 v1 = p32[e +     BLOCK];
            int2 v2 = p32[e + 2 * BLOCK];
            int2 v3 = p32[e + 3 * BLOCK];
            proc_edge(v0.x, v0.y, e,             tbase, charges, dist, tile);
            proc_edge(v1.x, v1.y, e +     BLOCK, tbase, charges, dist, tile);
            proc_edge(v2.x, v2.y, e + 2 * BLOCK, tbase, charges, dist, tile);
            proc_edge(v3.x, v3.y, e + 3 * BLOCK, tbase, charges, dist, tile);
        }
        for (; e < e1; e += BLOCK) {
            int2 v = p32[e];
            proc_edge(v.x, v.y, e, tbase, charges, dist, tile);
        }
    }
    __syncthreads();

    // Flush LDS tile to global with HW atomics.
    const float4* src = (const float4*)tile;
    for (int r = threadIdx.x; r < TILE_ATOMS; r += BLOCK) {
        int a = tbase + r;
        if (a >= n_atoms) break;                        // last-tile phantom rows
        float4 v = src[r];                              // ds_read_b128
        if (v.x != 0.f || v.y != 0.f || v.z != 0.f || v.w != 0.f) {
            float* o = out + (size_t)a * 4;
            unsafeAtomicAdd(o + 0, v.x);
            unsafeAtomicAdd(o + 1, v.y);
            unsafeAtomicAdd(o + 2, v.z);
            unsafeAtomicAdd(o + 3, v.w);
        }
    }
}

extern "C" void kernel_launch(void* const* d_in, const int* in_sizes, int n_in,
                              void* d_out, int out_size, void* d_ws, size_t ws_size,
                              hipStream_t stream) {
    const float4* charges = (const float4*)d_in[0];
    const void*   idx     = d_in[1];
    const float*  dist    = (const float*)d_in[2];
    int n_edges = in_sizes[2];
    int n_atoms = in_sizes[0] / 4;
    int ntiles  = (n_atoms + TILE_ATOMS - 1) / TILE_ATOMS;   // 10
    int epc     = (n_edges + CHUNKS - 1) / CHUNKS;
    int* flag   = (int*)d_ws;

    hipMemsetAsync(d_out, 0, (size_t)out_size * sizeof(float), stream);
    detect_idx64_kernel<<<1, 256, 0, stream>>>((const unsigned int*)idx, flag);
    fused_tile_kernel<<<ntiles * CHUNKS, BLOCK, 0, stream>>>(
        charges, idx, dist, (float*)d_out, flag, n_edges, n_atoms, ntiles, epc);
}

// Round 6
// 449.465 us; speedup vs baseline: 1.2906x; 1.2906x over previous
//
#include <hip/hip_runtime.h>

#define TILE_ATOMS 10000               // 10 tiles for 100K atoms
#define TILE_FLOATS (TILE_ATOMS * 4)   // 160000 B LDS = full CU capacity
#define BLOCK 1024
#define CPX 3                          // chunks per XCD
#define CHUNKS 24                      // 8 XCDs * CPX -> grid 240 on 256 CUs

// Detect whether neighbor_indices is int64 or int32 (odd u32 words all zero
// => int64 high halves). Replay-safe: value is identical every call.
__global__ void detect_idx64_kernel(const unsigned int* __restrict__ idx_u32,
                                    int* __restrict__ flag) {
    __shared__ int nonzero;
    if (threadIdx.x == 0) nonzero = 0;
    __syncthreads();
    unsigned int v = idx_u32[2 * (threadIdx.x +   0) + 1]
                   | idx_u32[2 * (threadIdx.x + 256) + 1]
                   | idx_u32[2 * (threadIdx.x + 512) + 1]
                   | idx_u32[2 * (threadIdx.x + 768) + 1];
    if (v != 0u) atomicAdd(&nonzero, 1);
    __syncthreads();
    if (threadIdx.x == 0) *flag = (nonzero == 0) ? 1 : 0;  // 1 => int64
}

#define RSQRT2 0.70710678118654752440f

__device__ __forceinline__ void side_atomics(float* __restrict__ tile,
                                             unsigned r, float4 g, float q) {
    atomicAdd(&tile[r * 4 + 0], g.x * q);
    atomicAdd(&tile[r * 4 + 1], g.y * q);
    atomicAdd(&tile[r * 4 + 2], g.z * q);
    atomicAdd(&tile[r * 4 + 3], g.w * q);
}

// Phase-split 4-deep scan: (1) 4 idx + 4 dist stream loads in flight,
// (2) 4 branchless pot computations, (3) all 8 conditional charges gathers
// issued back-to-back, (4) LDS atomics. Maximizes MLP on the dependent chain
// that round-5 counters showed to be the limiter (latency-bound, VALUBusy 21%).
template <bool F64>
__device__ __forceinline__ void scan_chunk(
    const void* __restrict__ idx, const float* __restrict__ dist,
    const float4* __restrict__ charges, float* __restrict__ tile,
    int tbase, int e0, int e1)
{
    int e = e0 + (int)threadIdx.x;
    for (; e + 3 * BLOCK < e1; e += 4 * BLOCK) {
        int a0, b0, a1, b1, a2, b2, a3, b3;
        if (F64) {
            const longlong2* p = (const longlong2*)idx;
            longlong2 w0 = p[e];
            longlong2 w1 = p[e +     BLOCK];
            longlong2 w2 = p[e + 2 * BLOCK];
            longlong2 w3 = p[e + 3 * BLOCK];
            a0 = (int)w0.x; b0 = (int)w0.y; a1 = (int)w1.x; b1 = (int)w1.y;
            a2 = (int)w2.x; b2 = (int)w2.y; a3 = (int)w3.x; b3 = (int)w3.y;
        } else {
            const int2* p = (const int2*)idx;
            int2 w0 = p[e];
            int2 w1 = p[e +     BLOCK];
            int2 w2 = p[e + 2 * BLOCK];
            int2 w3 = p[e + 3 * BLOCK];
            a0 = w0.x; b0 = w0.y; a1 = w1.x; b1 = w1.y;
            a2 = w2.x; b2 = w2.y; a3 = w3.x; b3 = w3.y;
        }
        float d0 = dist[e];
        float d1 = dist[e +     BLOCK];
        float d2 = dist[e + 2 * BLOCK];
        float d3 = dist[e + 3 * BLOCK];
        float q0 = 0.5f * erfcf(d0 * RSQRT2) * __builtin_amdgcn_rcpf(d0);
        float q1 = 0.5f * erfcf(d1 * RSQRT2) * __builtin_amdgcn_rcpf(d1);
        float q2 = 0.5f * erfcf(d2 * RSQRT2) * __builtin_amdgcn_rcpf(d2);
        float q3 = 0.5f * erfcf(d3 * RSQRT2) * __builtin_amdgcn_rcpf(d3);

        unsigned r0i = (unsigned)(a0 - tbase), r0j = (unsigned)(b0 - tbase);
        unsigned r1i = (unsigned)(a1 - tbase), r1j = (unsigned)(b1 - tbase);
        unsigned r2i = (unsigned)(a2 - tbase), r2j = (unsigned)(b2 - tbase);
        unsigned r3i = (unsigned)(a3 - tbase), r3j = (unsigned)(b3 - tbase);
        bool h0i = r0i < TILE_ATOMS, h0j = r0j < TILE_ATOMS;
        bool h1i = r1i < TILE_ATOMS, h1j = r1j < TILE_ATOMS;
        bool h2i = r2i < TILE_ATOMS, h2j = r2j < TILE_ATOMS;
        bool h3i = r3i < TILE_ATOMS, h3j = r3j < TILE_ATOMS;

        float4 g0i, g0j, g1i, g1j, g2i, g2j, g3i, g3j;
        if (h0i) g0i = charges[b0];
        if (h0j) g0j = charges[a0];
        if (h1i) g1i = charges[b1];
        if (h1j) g1j = charges[a1];
        if (h2i) g2i = charges[b2];
        if (h2j) g2j = charges[a2];
        if (h3i) g3i = charges[b3];
        if (h3j) g3j = charges[a3];

        if (h0i) side_atomics(tile, r0i, g0i, q0);
        if (h0j) side_atomics(tile, r0j, g0j, q0);
        if (h1i) side_atomics(tile, r1i, g1i, q1);
        if (h1j) side_atomics(tile, r1j, g1j, q1);
        if (h2i) side_atomics(tile, r2i, g2i, q2);
        if (h2j) side_atomics(tile, r2j, g2j, q2);
        if (h3i) side_atomics(tile, r3i, g3i, q3);
        if (h3j) side_atomics(tile, r3j, g3j, q3);
    }
    for (; e < e1; e += BLOCK) {
        int a, b;
        if (F64) { longlong2 w = ((const longlong2*)idx)[e]; a = (int)w.x; b = (int)w.y; }
        else     { int2      w = ((const int2*)idx)[e];      a = w.x;      b = w.y; }
        unsigned ri = (unsigned)(a - tbase), rj = (unsigned)(b - tbase);
        if (ri < TILE_ATOMS || rj < TILE_ATOMS) {
            float d = dist[e];
            float q = 0.5f * erfcf(d * RSQRT2) * __builtin_amdgcn_rcpf(d);
            if (ri < TILE_ATOMS) side_atomics(tile, ri, charges[b], q);
            if (rj < TILE_ATOMS) side_atomics(tile, rj, charges[a], q);
        }
    }
}

// Block (tile t, chunk c); XCD-affine: all blocks on XCD x share chunks
// x*CPX..x*CPX+2 -> the moving read window stays in that XCD's L2 (r5: FETCH
// 334->44MB). LDS-accumulate, flush via HW f32 atomics (replay-safe; plain
// cross-kernel stores through d_ws are NOT — r3 lesson).
__global__ __launch_bounds__(BLOCK, 1) void fused_tile_kernel(
    const float4* __restrict__ charges, const void* __restrict__ idx,
    const float* __restrict__ dist, float* __restrict__ out,
    const int* __restrict__ flag64,
    int n_edges, int n_atoms, int ntiles, int epc)
{
    __shared__ float tile[TILE_FLOATS];
    int x  = blockIdx.x & 7;              // XCD (round-robin dispatch, m09)
    int m  = blockIdx.x >> 3;
    int t  = m % ntiles;
    int cw = m / ntiles;                  // 0..CPX-1
    int c  = x * CPX + cw;
    int tbase = t * TILE_ATOMS;
    for (int i = threadIdx.x; i < TILE_FLOATS; i += BLOCK) tile[i] = 0.f;
    bool f64 = (*flag64 != 0);
    __syncthreads();

    int e0 = c * epc;
    int e1 = min(n_edges, e0 + epc);
    if (f64) scan_chunk<true >(idx, dist, charges, tile, tbase, e0, e1);
    else     scan_chunk<false>(idx, dist, charges, tile, tbase, e0, e1);
    __syncthreads();

    const float4* src = (const float4*)tile;
    for (int r = threadIdx.x; r < TILE_ATOMS; r += BLOCK) {
        int a = tbase + r;
        if (a >= n_atoms) break;
        float4 v = src[r];
        if (v.x != 0.f || v.y != 0.f || v.z != 0.f || v.w != 0.f) {
            float* o = out + (size_t)a * 4;
            unsafeAtomicAdd(o + 0, v.x);
            unsafeAtomicAdd(o + 1, v.y);
            unsafeAtomicAdd(o + 2, v.z);
            unsafeAtomicAdd(o + 3, v.w);
        }
    }
}

extern "C" void kernel_launch(void* const* d_in, const int* in_sizes, int n_in,
                              void* d_out, int out_size, void* d_ws, size_t ws_size,
                              hipStream_t stream) {
    const float4* charges = (const float4*)d_in[0];
    const void*   idx     = d_in[1];
    const float*  dist    = (const float*)d_in[2];
    int n_edges = in_sizes[2];
    int n_atoms = in_sizes[0] / 4;
    int ntiles  = (n_atoms + TILE_ATOMS - 1) / TILE_ATOMS;   // 10
    int epc     = (n_edges + CHUNKS - 1) / CHUNKS;
    int* flag   = (int*)d_ws;

    hipMemsetAsync(d_out, 0, (size_t)out_size * sizeof(float), stream);
    detect_idx64_kernel<<<1, 256, 0, stream>>>((const unsigned int*)idx, flag);
    fused_tile_kernel<<<ntiles * CHUNKS, BLOCK, 0, stream>>>(
        charges, idx, dist, (float*)d_out, flag, n_edges, n_atoms, ntiles, epc);
}